// Round 10
// baseline (406.616 us; speedup 1.0000x reference)
//
#include <hip/hip_runtime.h>
#include <hip/hip_bf16.h>

// LSTM B=8192,T=512,I=3,H=25 + linear[H->1], bf16 MFMA 16x16x32.
// R10: R5-R9 invariant: wall ~560-675 cy/CU/tile-step regardless of waves/
// barriers/ILP -> saturated HW pipe. Trans floor model: 8 trans/unit-step on
// a 1/8-rate trans pipe = 191 us chip-wide; R4's half-SIMD structure hit 378
// (=2x floor), R5/6/8 at 1.25-1.33x floor. Fix: move exp2 OFF the trans pipe
// -> pure-VALU exp2 (med3 clamp + floor + deg-5 poly + exponent-int-add,
// ~11 full-rate insts, rel err 2e-7). Only 3 v_rcp/chain stay on trans.
// Structure otherwise identical to R8 (256 blocks x 7 waves, 2 tiles/block,
// one barrier/step).

#define TSTEPS 512
#define ISZ 3
#define HSZ 25
#define NW 7
#define CHUNK 256
#define TSTRIDE 40          // shorts per batch row (80 B)

typedef __attribute__((ext_vector_type(8))) short bf16x8;
typedef __attribute__((ext_vector_type(4))) float f32x4;

__device__ __forceinline__ unsigned short bf16_bits(float v) {
    return __builtin_bit_cast(unsigned short, __float2bfloat16(v));
}
__device__ __forceinline__ unsigned int pack_bf16(float lo, float hi) {
    return ((unsigned int)bf16_bits(hi) << 16) | (unsigned int)bf16_bits(lo);
}

// Pure-VALU exp2: no trans-pipe use. Clamp keeps exponent-add in range and
// keeps e finite (so inf never enters the products; overflow->inf->rcp->0
// still yields correct saturated gates).
__device__ __forceinline__ float exp2_fast(float x) {
    x = __builtin_amdgcn_fmed3f(x, -110.0f, 110.0f);
    const float n = __builtin_floorf(x);
    const float f = x - n;                 // [0,1)
    float p = fmaf(f, 0.00133335581f, 0.00961812910f);
    p = fmaf(f, p, 0.0555041087f);
    p = fmaf(f, p, 0.240226507f);
    p = fmaf(f, p, 0.693147180f);
    p = fmaf(f, p, 1.0f);                  // 2^f, rel err ~2e-7
    const int ni = (int)n;
    return __builtin_bit_cast(float, __builtin_bit_cast(int, p) + (ni << 23));
}

// LSTM cell: c' = sig(a1)*c + sig(a0)*tanh(a2); h = sig(a3)*tanh(c')
// 5 VALU-exp2 + 3 v_rcp per chain (trans-pipe load cut 8 -> 3).
__device__ __forceinline__ void lstm_act(const f32x4 acc, float& c, float& h) {
    const float K1 = 1.442695040888963f;   // log2 e
    const float K2 = 2.885390081777927f;   // 2 log2 e
    const float e0 = exp2_fast(-K1 * acc[0]);
    const float e1 = exp2_fast(-K1 * acc[1]);
    const float e2 = exp2_fast(-K2 * acc[2]);
    const float e3 = exp2_fast(-K1 * acc[3]);
    const float f  = __builtin_amdgcn_rcpf(1.0f + e1);
    const float ig = (1.0f - e2) * __builtin_amdgcn_rcpf((1.0f + e0) * (1.0f + e2));
    c = fmaf(f, c, ig);
    const float ec = exp2_fast(-K2 * c);
    h = (1.0f - ec) * __builtin_amdgcn_rcpf((1.0f + e3) * (1.0f + ec));
}

__global__ __launch_bounds__(NW * 64) void lstm_mfma(
    const float* __restrict__ x,      // [B, T, I]
    const float* __restrict__ w_ih,   // [4H, I]
    const float* __restrict__ w_hh,   // [4H, H]
    const float* __restrict__ b_ih,   // [4H]
    const float* __restrict__ b_hh,   // [4H]
    const float* __restrict__ w_lin,  // [1, H]
    const float* __restrict__ b_lin,  // [1]
    float* __restrict__ out)          // [B, 1]
{
    __shared__ uint2 xpk[2][CHUNK][16];       // 64 KB packed bf16 x (+1.0)
    __shared__ short hb[2][2][16 * TSTRIDE];  // [parity][tile] h rows, 5 KB
    __shared__ float outred[2][NW][16];

    const int tid  = threadIdx.x;
    const int w    = tid >> 6;       // wave 0..6: frag T=w (units 4w..4w+3)
    const int lane = tid & 63;
    const int n    = lane & 15;      // batch within tile
    const int q    = lane >> 4;      // quad -> unit u = 4w + q
    const bool isq0 = (q == 0);
    const int u    = 4 * w + q;
    const bool act = (w < 6) || isq0;          // u < 25

    // zero both h parity buffers, both tiles (pad slots stay 0 forever)
    for (int i = tid; i < 2 * 2 * 16 * TSTRIDE; i += NW * 64) ((short*)hb)[i] = 0;

    // ---- stage one 256-step chunk of x for both tiles (pre-packed bf16) ----
    auto stage = [&](int c0) {
        const int bsel = tid & 31;                 // batch in the 32-batch pair
        const int tile = bsel >> 4, nn = bsel & 15;
        const float* __restrict__ g =
            x + (size_t)(blockIdx.x * 32 + bsel) * (TSTEPS * ISZ) + c0 * ISZ;
        for (int tg = tid >> 5; tg < CHUNK / 4; tg += 14) {   // 4-step groups
            const float4* f4 = (const float4*)(g + tg * 12);
            float4 a = f4[0], b4 = f4[1], c4 = f4[2];
            const float s[4][3] = { {a.x, a.y, a.z}, {a.w, b4.x, b4.y},
                                    {b4.z, b4.w, c4.x}, {c4.y, c4.z, c4.w} };
            #pragma unroll
            for (int uu = 0; uu < 4; ++uu) {
                uint2 d;
                d.x = pack_bf16(s[uu][0], s[uu][1]);
                d.y = pack_bf16(s[uu][2], 1.0f);
                xpk[tile][tg * 4 + uu][nn] = d;
            }
        }
    };
    stage(0);

    // ---- this wave's A fragment (loaded once, register-resident) ----
    // A[r=16w+n][k=q*8+j]; row r=4u'+g (unit-major); k: [w_ih 0..2, bias 3, w_hh 4..28]
    bf16x8 afrag;
    #pragma unroll
    for (int j = 0; j < 8; ++j) {
        const int k = q * 8 + j;
        const int r = 16 * w + n;
        const int uu = r >> 2, g = r & 3;
        float v = 0.0f;
        if (uu < HSZ) {
            const int orow = g * HSZ + uu;         // original i,f,g,o row order
            if (k < ISZ)            v = w_ih[orow * ISZ + k];
            else if (k == ISZ)      v = b_ih[orow] + b_hh[orow];
            else if (k < 4 + HSZ)   v = w_hh[orow * HSZ + (k - 4)];
        }
        afrag[j] = (short)bf16_bits(v);
    }

    __syncthreads();

    float cA = 0.f, hA = 0.f, cB = 0.f, hB = 0.f;

    #pragma unroll 1
    for (int t = 0; t < TSTEPS; ++t) {
        if (t == CHUNK) {                 // entry synced by barrier of t-1
            stage(CHUNK);
            __syncthreads();
        }
        const int ts = t & (CHUNK - 1);
        const uint2 xA = xpk[0][ts][n];
        const uint2 xB = xpk[1][ts][n];
        // both tiles' h(t) visible since barrier(t-1): read both at loop top,
        // latencies overlap; chains below are independent (intra-wave ILP)
        bf16x8 bfA = *reinterpret_cast<const bf16x8*>(&hb[t & 1][0][n * TSTRIDE + q * 8]);
        bf16x8 bfB = *reinterpret_cast<const bf16x8*>(&hb[t & 1][1][n * TSTRIDE + q * 8]);

        uint4 biA = __builtin_bit_cast(uint4, bfA);
        uint4 biB = __builtin_bit_cast(uint4, bfB);
        if (isq0) {
            biA.x = xA.x; biA.y = xA.y;
            biB.x = xB.x; biB.y = xB.y;
        }
        const f32x4 accA = __builtin_amdgcn_mfma_f32_16x16x32_bf16(
            afrag, __builtin_bit_cast(bf16x8, biA),
            (f32x4){0.f, 0.f, 0.f, 0.f}, 0, 0, 0);
        const f32x4 accB = __builtin_amdgcn_mfma_f32_16x16x32_bf16(
            afrag, __builtin_bit_cast(bf16x8, biB),
            (f32x4){0.f, 0.f, 0.f, 0.f}, 0, 0, 0);

        lstm_act(accA, cA, hA);
        lstm_act(accB, cB, hB);

        if (act) {
            hb[(t + 1) & 1][0][n * TSTRIDE + 4 + u] = (short)bf16_bits(hA);
            hb[(t + 1) & 1][1][n * TSTRIDE + 4 + u] = (short)bf16_bits(hB);
        }
        __syncthreads();                  // ONE barrier per step, both tiles
    }

    // ---- final linear: out[b] = sum_u w_lin[u]*h[u] + b_lin ----
    float vA = 0.f, vB = 0.f;
    if (act) { vA = w_lin[u] * hA; vB = w_lin[u] * hB; }
    vA += __shfl_xor(vA, 16); vA += __shfl_xor(vA, 32);
    vB += __shfl_xor(vB, 16); vB += __shfl_xor(vB, 32);
    if (lane < 16) { outred[0][w][lane] = vA; outred[1][w][lane] = vB; }
    __syncthreads();
    if (tid < 32) {
        const int tile = tid >> 4, nn = tid & 15;
        float s = b_lin[0];
        #pragma unroll
        for (int k = 0; k < NW; ++k) s += outred[tile][k][nn];
        out[blockIdx.x * 32 + tile * 16 + nn] = s;
    }
}

extern "C" void kernel_launch(void* const* d_in, const int* in_sizes, int n_in,
                              void* d_out, int out_size, void* d_ws, size_t ws_size,
                              hipStream_t stream) {
    const float* x     = (const float*)d_in[0];
    const float* w_ih  = (const float*)d_in[1];
    const float* w_hh  = (const float*)d_in[2];
    const float* b_ih  = (const float*)d_in[3];
    const float* b_hh  = (const float*)d_in[4];
    const float* w_lin = (const float*)d_in[5];
    const float* b_lin = (const float*)d_in[6];
    float* out = (float*)d_out;

    lstm_mfma<<<8192 / 32, NW * 64, 0, stream>>>(x, w_ih, w_hh, b_ih, b_hh,
                                                 w_lin, b_lin, out);
}

// Round 11
// 269.036 us; speedup vs baseline: 1.5114x; 1.5114x over previous
//
#include <hip/hip_runtime.h>
#include <hip/hip_bf16.h>

// LSTM B=8192,T=512,I=3,H=25 + linear[H->1], bf16 MFMA 16x16x32.
// R11: base = R6 (best, 238us: 512 blocks x 7 waves, 1 tile, 2 chains/CU).
// R10 proved trans pipe NOT saturated (VALU-poly exp regressed 254->360);
// the wall is per-step serial chain + issue. Changes:
//  - x pre-merged into the h-row by wave 6 (underloaded: only q0 acts):
//    its q1 lanes write x(t+1) bf16 into slots 0..3 of the next-parity row.
//    bfrag is now a bare ds_read_b128 -> MFMA (no xpk read + overlay on the
//    critical path for waves 0..5).
//  - chunk restage at t=CHUNK-1 with its own barrier (x prefetch crosses
//    the chunk boundary).
//  - loop unrolled x2 over parity; v_exp activations (R10 revert).

#define TSTEPS 512
#define ISZ 3
#define HSZ 25
#define NW 7
#define CHUNK 256
#define TSTRIDE 40          // shorts per batch row (80 B)

typedef __attribute__((ext_vector_type(8))) short bf16x8;
typedef __attribute__((ext_vector_type(4))) float f32x4;

__device__ __forceinline__ unsigned short bf16_bits(float v) {
    return __builtin_bit_cast(unsigned short, __float2bfloat16(v));
}
__device__ __forceinline__ unsigned int pack_bf16(float lo, float hi) {
    return ((unsigned int)bf16_bits(hi) << 16) | (unsigned int)bf16_bits(lo);
}

// LSTM cell: c' = sig(a1)*c + sig(a0)*tanh(a2); h = sig(a3)*tanh(c')
// 5 v_exp + 3 v_rcp per chain (R5-R8 numerics, absmax 0.0117 verified).
__device__ __forceinline__ void lstm_act(const f32x4 acc, float& c, float& h) {
    const float K1 = 1.442695040888963f;   // log2 e
    const float K2 = 2.885390081777927f;   // 2 log2 e
    const float e0 = __builtin_amdgcn_exp2f(-K1 * acc[0]);
    const float e1 = __builtin_amdgcn_exp2f(-K1 * acc[1]);
    const float e2 = __builtin_amdgcn_exp2f(fminf(-K2 * acc[2], 126.0f));
    const float e3 = __builtin_amdgcn_exp2f(-K1 * acc[3]);
    const float f  = __builtin_amdgcn_rcpf(1.0f + e1);
    const float ig = (1.0f - e2) * __builtin_amdgcn_rcpf((1.0f + e0) * (1.0f + e2));
    c = fmaf(f, c, ig);
    const float ec = __builtin_amdgcn_exp2f(fminf(-K2 * c, 126.0f));
    h = (1.0f - ec) * __builtin_amdgcn_rcpf((1.0f + e3) * (1.0f + ec));
}

__global__ __launch_bounds__(NW * 64) void lstm_mfma(
    const float* __restrict__ x,      // [B, T, I]
    const float* __restrict__ w_ih,   // [4H, I]
    const float* __restrict__ w_hh,   // [4H, H]
    const float* __restrict__ b_ih,   // [4H]
    const float* __restrict__ b_hh,   // [4H]
    const float* __restrict__ w_lin,  // [1, H]
    const float* __restrict__ b_lin,  // [1]
    float* __restrict__ out)          // [B, 1]
{
    __shared__ uint2 xpk[CHUNK][16];          // 32 KB packed bf16 x (+1.0)
    __shared__ short hb[2][16 * TSTRIDE];     // parity-buffered B-rows
    __shared__ float outred[NW][16];

    const int tid  = threadIdx.x;
    const int w    = tid >> 6;       // wave 0..6: frag T=w (units 4w..4w+3)
    const int lane = tid & 63;
    const int n    = lane & 15;      // batch within tile
    const int q    = lane >> 4;      // quad -> unit u = 4w + q
    const int u    = 4 * w + q;
    const bool actm = (w < 6) || (q == 0);     // u < 25
    const bool isxw = (w == 6) && (q == 1);    // x-writer lanes (16)

    // zero both parity buffers (h(0)=0; pad slots stay 0 forever)
    for (int i = tid; i < 2 * 16 * TSTRIDE; i += NW * 64) ((short*)hb)[i] = 0;

    // ---- stage one 256-step chunk of x (pre-packed bf16), 256 threads ----
    auto stage = [&](int c0) {
        if (tid < 256) {
            const int bsel = tid >> 4, sub16 = tid & 15;
            const float* __restrict__ g =
                x + (size_t)(blockIdx.x * 16 + bsel) * (TSTEPS * ISZ) + c0 * ISZ;
            #pragma unroll
            for (int it = 0; it < 4; ++it) {
                const int tg = sub16 + 16 * it;        // 4-step groups 0..63
                const float4* f4 = (const float4*)(g + tg * 12);
                float4 a = f4[0], b4 = f4[1], c4 = f4[2];
                const float s[4][3] = { {a.x, a.y, a.z}, {a.w, b4.x, b4.y},
                                        {b4.z, b4.w, c4.x}, {c4.y, c4.z, c4.w} };
                #pragma unroll
                for (int uu = 0; uu < 4; ++uu) {
                    uint2 d;
                    d.x = pack_bf16(s[uu][0], s[uu][1]);
                    d.y = pack_bf16(s[uu][2], 1.0f);
                    xpk[tg * 4 + uu][bsel] = d;
                }
            }
        }
    };
    stage(0);

    // ---- this wave's A fragment (loaded once, register-resident) ----
    // A[r=16w+n][k=q*8+j]; row r=4u'+g (unit-major); k: [w_ih 0..2, bias 3, w_hh 4..28]
    bf16x8 afrag;
    #pragma unroll
    for (int j = 0; j < 8; ++j) {
        const int k = q * 8 + j;
        const int r = 16 * w + n;
        const int uu = r >> 2, g = r & 3;
        float v = 0.0f;
        if (uu < HSZ) {
            const int orow = g * HSZ + uu;             // original i,f,g,o order
            if (k < ISZ)            v = w_ih[orow * ISZ + k];
            else if (k == ISZ)      v = b_ih[orow] + b_hh[orow];
            else if (k < 4 + HSZ)   v = w_hh[orow * HSZ + (k - 4)];
        }
        afrag[j] = (short)bf16_bits(v);
    }

    __syncthreads();
    // seed x(0) into parity-0 rows (slots 0..3), by the x-writer lanes
    if (isxw) *(uint2*)&hb[0][n * TSTRIDE] = xpk[0][n];
    __syncthreads();

    float c = 0.f, h = 0.f;
    const int rdoff = n * TSTRIDE + q * 8;
    const int wroff = n * TSTRIDE + 4 + u;
    const int xwoff = n * TSTRIDE;

    auto step = [&](int t, short* __restrict__ rb, short* __restrict__ wb) {
        // bare ds_read_b128 -> MFMA (x already merged into slots 0..3)
        const bf16x8 bfrag = *reinterpret_cast<const bf16x8*>(rb + rdoff);
        const f32x4 acc = __builtin_amdgcn_mfma_f32_16x16x32_bf16(
            afrag, bfrag, (f32x4){0.f, 0.f, 0.f, 0.f}, 0, 0, 0);
        lstm_act(acc, c, h);
        if (actm) wb[wroff] = (short)bf16_bits(h);
        if (isxw) *(uint2*)&wb[xwoff] = xpk[(t + 1) & (CHUNK - 1)][n];
        __syncthreads();
    };

    #pragma unroll 1
    for (int t = 0; t < TSTEPS; t += 2) {
        if (t == CHUNK - 2) {
            // t=254: after this pair's first step we'd prefetch x(256) ->
            // restage must land between x(255) read (iter 253) and x(256)
            // read (iter 255). Do it here, before the pair.
            step(t, hb[0], hb[1]);        // t=254 (even), reads x(255) staged? no:
            // NOTE: x(255) was consumed at iter 254's writer read BEFORE this
            // restage? -- see ordering note below: writer at iter 253 read
            // x(254), iter 254 reads x(255) (old chunk) AFTER restage would
            // clobber it. So restage strictly AFTER step(254):
            stage(CHUNK);
            __syncthreads();
            step(t + 1, hb[1], hb[0]);    // t=255: writer reads new x(256&255=0)
            continue;
        }
        step(t, hb[0], hb[1]);
        step(t + 1, hb[1], hb[0]);
    }

    // ---- final linear: out[b] = sum_u w_lin[u]*h[u] + b_lin ----
    float v = 0.f;
    if (actm) v = w_lin[u] * h;
    v += __shfl_xor(v, 16);
    v += __shfl_xor(v, 32);
    if (lane < 16) outred[w][lane] = v;
    __syncthreads();
    if (tid < 16) {
        float s = b_lin[0];
        #pragma unroll
        for (int k = 0; k < NW; ++k) s += outred[k][tid];
        out[blockIdx.x * 16 + tid] = s;
    }
}

extern "C" void kernel_launch(void* const* d_in, const int* in_sizes, int n_in,
                              void* d_out, int out_size, void* d_ws, size_t ws_size,
                              hipStream_t stream) {
    const float* x     = (const float*)d_in[0];
    const float* w_ih  = (const float*)d_in[1];
    const float* w_hh  = (const float*)d_in[2];
    const float* b_ih  = (const float*)d_in[3];
    const float* b_hh  = (const float*)d_in[4];
    const float* w_lin = (const float*)d_in[5];
    const float* b_lin = (const float*)d_in[6];
    float* out = (float*)d_out;

    lstm_mfma<<<8192 / 16, NW * 64, 0, stream>>>(x, w_ih, w_hh, b_ih, b_hh,
                                                 w_lin, b_lin, out);
}

// Round 12
// 258.244 us; speedup vs baseline: 1.5745x; 1.0418x over previous
//
#include <hip/hip_runtime.h>
#include <hip/hip_bf16.h>

// LSTM B=8192,T=512,I=3,H=25 + linear[H->1], bf16 MFMA 16x16x32.
// R12: R11 calibrated model: period(2 tile-steps/CU) = per-SIMD issue (534 =
// 3.5 waves x 152cy) + exposed chain (420). This round cuts ISSUE:
//  - pk-packed act glue (v_pk_mul/add_f32 on gate pairs)
//  - UNMASKED h-writes: u=25..27 lanes write garbage into B-slots 29..31,
//    which hit A's zero pad columns (k>=29 -> A=0); garbage is finite
//    (acc=0 rows). Removes per-step exec-mask juggling in all waves.
//  - restage check hoisted: t-loop split into two chunk halves.
// Structure otherwise R11: 512 blocks x 7 waves, x pre-merged into h-rows by
// wave 6 q1, bare ds_read_b128 -> MFMA, one barrier/step.

#define TSTEPS 512
#define ISZ 3
#define HSZ 25
#define NW 7
#define CHUNK 256
#define TSTRIDE 40          // shorts per batch row (80 B)

typedef __attribute__((ext_vector_type(8))) short bf16x8;
typedef __attribute__((ext_vector_type(4))) float f32x4;
typedef __attribute__((ext_vector_type(2))) float v2f;

__device__ __forceinline__ unsigned short bf16_bits(float v) {
    return __builtin_bit_cast(unsigned short, __float2bfloat16(v));
}
__device__ __forceinline__ unsigned int pack_bf16(float lo, float hi) {
    return ((unsigned int)bf16_bits(hi) << 16) | (unsigned int)bf16_bits(lo);
}

__global__ __launch_bounds__(NW * 64) void lstm_mfma(
    const float* __restrict__ x,      // [B, T, I]
    const float* __restrict__ w_ih,   // [4H, I]
    const float* __restrict__ w_hh,   // [4H, H]
    const float* __restrict__ b_ih,   // [4H]
    const float* __restrict__ b_hh,   // [4H]
    const float* __restrict__ w_lin,  // [1, H]
    const float* __restrict__ b_lin,  // [1]
    float* __restrict__ out)          // [B, 1]
{
    __shared__ uint2 xpk[CHUNK][16];          // 32 KB packed bf16 x (+1.0)
    __shared__ short hb[2][16 * TSTRIDE];     // parity-buffered B-rows
    __shared__ float outred[NW][16];

    const int tid  = threadIdx.x;
    const int w    = tid >> 6;       // wave 0..6: frag T=w (units 4w..4w+3)
    const int lane = tid & 63;
    const int n    = lane & 15;      // batch within tile
    const int q    = lane >> 4;      // quad -> unit u = 4w + q
    const int u    = 4 * w + q;
    const bool isxw = (w == 6) && (q == 1);    // x-writer lanes (16)

    // zero both parity buffers (h(0)=0)
    for (int i = tid; i < 2 * 16 * TSTRIDE; i += NW * 64) ((short*)hb)[i] = 0;

    // ---- stage one 256-step chunk of x (pre-packed bf16), 256 threads ----
    auto stage = [&](int c0) {
        if (tid < 256) {
            const int bsel = tid >> 4, sub16 = tid & 15;
            const float* __restrict__ g =
                x + (size_t)(blockIdx.x * 16 + bsel) * (TSTEPS * ISZ) + c0 * ISZ;
            #pragma unroll
            for (int it = 0; it < 4; ++it) {
                const int tg = sub16 + 16 * it;        // 4-step groups 0..63
                const float4* f4 = (const float4*)(g + tg * 12);
                float4 a = f4[0], b4 = f4[1], c4 = f4[2];
                const float s[4][3] = { {a.x, a.y, a.z}, {a.w, b4.x, b4.y},
                                        {b4.z, b4.w, c4.x}, {c4.y, c4.z, c4.w} };
                #pragma unroll
                for (int uu = 0; uu < 4; ++uu) {
                    uint2 d;
                    d.x = pack_bf16(s[uu][0], s[uu][1]);
                    d.y = pack_bf16(s[uu][2], 1.0f);
                    xpk[tg * 4 + uu][bsel] = d;
                }
            }
        }
    };
    stage(0);

    // ---- this wave's A fragment (loaded once, register-resident) ----
    // A[r=16w+n][k=q*8+j]; row r=4u'+g (unit-major); k: [w_ih 0..2, bias 3, w_hh 4..28]
    bf16x8 afrag;
    #pragma unroll
    for (int j = 0; j < 8; ++j) {
        const int k = q * 8 + j;
        const int r = 16 * w + n;
        const int uu = r >> 2, g = r & 3;
        float v = 0.0f;
        if (uu < HSZ) {
            const int orow = g * HSZ + uu;             // original i,f,g,o order
            if (k < ISZ)            v = w_ih[orow * ISZ + k];
            else if (k == ISZ)      v = b_ih[orow] + b_hh[orow];
            else if (k < 4 + HSZ)   v = w_hh[orow * HSZ + (k - 4)];
        }
        afrag[j] = (short)bf16_bits(v);
    }

    __syncthreads();
    // seed x(0) into parity-0 rows (slots 0..3)
    if (isxw) *(uint2*)&hb[0][n * TSTRIDE] = xpk[0][n];
    __syncthreads();

    float c = 0.f, h = 0.f;
    const int rdoff = n * TSTRIDE + q * 8;
    const int wroff = n * TSTRIDE + 4 + u;    // u up to 27 -> slot <= 31 (pad, A=0)
    const int xwoff = n * TSTRIDE;
    const float K1 = 1.442695040888963f;      // log2 e
    const float K2 = 2.885390081777927f;      // 2 log2 e

    auto step = [&](int t, short* __restrict__ rb, short* __restrict__ wb) {
        // bare ds_read_b128 -> MFMA (x already merged into slots 0..3)
        const bf16x8 bfrag = *reinterpret_cast<const bf16x8*>(rb + rdoff);
        const f32x4 acc = __builtin_amdgcn_mfma_f32_16x16x32_bf16(
            afrag, bfrag, (f32x4){0.f, 0.f, 0.f, 0.f}, 0, 0, 0);

        // acts: same math as R11, glue packed for v_pk_* issue
        v2f p01 = (v2f){acc[0], acc[1]} * (v2f){-K1, -K1};
        v2f p23 = (v2f){acc[2], acc[3]} * (v2f){-K2, -K1};
        const float e0 = __builtin_amdgcn_exp2f(p01.x);
        const float e1 = __builtin_amdgcn_exp2f(p01.y);
        const float e2 = __builtin_amdgcn_exp2f(fminf(p23.x, 126.0f));
        const float e3 = __builtin_amdgcn_exp2f(p23.y);
        v2f s02 = (v2f){e0, e2} + (v2f){1.0f, 1.0f};
        v2f s13 = (v2f){e1, e3} + (v2f){1.0f, 1.0f};
        const float f  = __builtin_amdgcn_rcpf(s13.x);
        const float ig = (1.0f - e2) * __builtin_amdgcn_rcpf(s02.x * s02.y);
        c = fmaf(f, c, ig);
        const float ec = __builtin_amdgcn_exp2f(fminf(-K2 * c, 126.0f));
        h = (1.0f - ec) * __builtin_amdgcn_rcpf(s13.y * (1.0f + ec));

        wb[wroff] = (short)bf16_bits(h);           // unmasked (pad-slot trick)
        if (isxw) *(uint2*)&wb[xwoff] = xpk[(t + 1) & (CHUNK - 1)][n];
        __syncthreads();
    };

    // ---- chunk 0: steps 0..253 ----
    #pragma unroll 1
    for (int p = 0; p < 127; ++p) {
        const int t = 2 * p;
        step(t, hb[0], hb[1]);
        step(t + 1, hb[1], hb[0]);
    }
    // boundary: step 254 reads x(255) (old chunk); restage; step 255 reads x(256)
    step(254, hb[0], hb[1]);
    stage(CHUNK);
    __syncthreads();
    step(255, hb[1], hb[0]);
    // ---- chunk 1: steps 256..511 ----
    #pragma unroll 1
    for (int p = 0; p < 128; ++p) {
        const int t = 256 + 2 * p;
        step(t, hb[0], hb[1]);
        step(t + 1, hb[1], hb[0]);
    }

    // ---- final linear: out[b] = sum_u w_lin[u]*h[u] + b_lin ----
    const float wl = (u < HSZ) ? w_lin[u] : 0.0f;
    float v = wl * h;
    v += __shfl_xor(v, 16);
    v += __shfl_xor(v, 32);
    if (lane < 16) outred[w][lane] = v;
    __syncthreads();
    if (tid < 16) {
        float s = b_lin[0];
        #pragma unroll
        for (int k = 0; k < NW; ++k) s += outred[k][tid];
        out[blockIdx.x * 16 + tid] = s;
    }
}

extern "C" void kernel_launch(void* const* d_in, const int* in_sizes, int n_in,
                              void* d_out, int out_size, void* d_ws, size_t ws_size,
                              hipStream_t stream) {
    const float* x     = (const float*)d_in[0];
    const float* w_ih  = (const float*)d_in[1];
    const float* w_hh  = (const float*)d_in[2];
    const float* b_ih  = (const float*)d_in[3];
    const float* b_hh  = (const float*)d_in[4];
    const float* w_lin = (const float*)d_in[5];
    const float* b_lin = (const float*)d_in[6];
    float* out = (float*)d_out;

    lstm_mfma<<<8192 / 16, NW * 64, 0, stream>>>(x, w_ih, w_hh, b_ih, b_hh,
                                                 w_lin, b_lin, out);
}